// Round 5
// baseline (393.665 us; speedup 1.0000x reference)
//
#include <hip/hip_runtime.h>

// p/v trajectory double-scan, K = 2^23 fp32 3-vectors — SINGLE-PASS decoupled lookback.
// Aligned-stream formulation: z_m = f[m]; E_i = excl prefix(z); H_i = sum_{m<=i} E_m.
// S_i = f0 + E_i, T_i = (i+1) f0 + H_i;
//   v_i = v0 + Cc*S_i + GZ*(i+1) e3
//   p_i = p0 + DT*(i+1)*v0 + DT*Cc*T_i - DT/2*Cc*S_i + DT/2*GZ*(i+1)^2 e3
// Segment operator on (A = sum z, W = sum of seg-local excl prefix):
//   prepend seg X (len L) before acc covering m blocks: accH += W_X + m*CHUNK*A_X; accE += A_X.
// Block aggregates published with release flag=1; inclusive prefixes with flag=2;
// wave-0 64-wide lookback composes exclusive (Eg, Hg). All IO through the padded
// LDS transpose buffer (round-4 lesson: strided nt stores amplify HBM writes 2.6x).

namespace {
constexpr int  KE    = 8388608;               // 2^23
constexpr int  CHUNK = 2048;                  // elements per block
constexpr int  NB    = KE / CHUNK;            // 4096
constexpr int  BLOCK = 256;
constexpr int  R     = CHUNK / BLOCK;         // 8 elements/thread
constexpr int  NF4   = 3 * CHUNK / 4;         // 1536 float4s per block
constexpr float DTc = 0.01f;
constexpr float Cc  = 0.01f / 1.5f;           // DT/M
constexpr float GZ  = -0.01f * 9.81f;         // DT * (-G)
typedef float f32x4 __attribute__((ext_vector_type(4)));
__device__ __forceinline__ int physf4(int q) { return 7 * (q / 6) + q % 6; }
}

__global__ __launch_bounds__(BLOCK, 5) void k_fused(const float* __restrict__ f,
                                                    unsigned int* __restrict__ flag,
                                                    float* __restrict__ pay,      // [NB][12]: A[3],W[3],Eincl[3],Hincl[3]
                                                    const float* __restrict__ p0v,
                                                    const float* __restrict__ v0v,
                                                    float* __restrict__ out) {
  const int b = blockIdx.x, t = threadIdx.x;
  const int lane = t & 63, wid = t >> 6;
  const long start = (long)b * CHUNK;

  __shared__ f32x4 buf[7 * BLOCK];    // 28672 B padded transpose buffer
  __shared__ float wag[4][6];
  __shared__ float shEH[6];

  // ---- 1. coalesced global load -> LDS (blocked-padded layout)
  {
    const f32x4* src = (const f32x4*)(f + 3 * start);
#pragma unroll
    for (int it = 0; it < 6; ++it) {
      const int q = t + BLOCK * it;
      buf[physf4(q)] = src[q];
    }
  }
  __syncthreads();

  // ---- 2. thread's 8 elements = 6 float4 LDS reads at stride-7 base
  float z[3 * R];
#pragma unroll
  for (int u = 0; u < 6; ++u) {
    f32x4 d = buf[7 * t + u];
    z[4 * u] = d.x; z[4 * u + 1] = d.y; z[4 * u + 2] = d.z; z[4 * u + 3] = d.w;
  }

  // per-thread aggregates: A = sum z, W = sum (R-1-e)*z
  float tS[3] = {0, 0, 0}, tT[3] = {0, 0, 0};
#pragma unroll
  for (int e = 0; e < R; ++e) {
    const float wt = (float)(R - 1 - e);
#pragma unroll
    for (int q = 0; q < 3; ++q) { float v = z[3 * e + q]; tS[q] += v; tT[q] += wt * v; }
  }
  // wave Kogge-Stone with (A,W,L) operator
#pragma unroll
  for (int d = 1; d < 64; d <<= 1) {
    float pS[3], pT[3];
#pragma unroll
    for (int q = 0; q < 3; ++q) { pS[q] = __shfl_up(tS[q], d); pT[q] = __shfl_up(tT[q], d); }
    if (lane >= d) {
      const float Ld = (float)(R * d);
#pragma unroll
      for (int q = 0; q < 3; ++q) { tT[q] = pT[q] + Ld * pS[q] + tT[q]; tS[q] += pS[q]; }
    }
  }
  float eS[3], eT[3];
#pragma unroll
  for (int q = 0; q < 3; ++q) { eS[q] = __shfl_up(tS[q], 1); eT[q] = __shfl_up(tT[q], 1); }
  if (lane == 0) {
#pragma unroll
    for (int q = 0; q < 3; ++q) { eS[q] = 0.f; eT[q] = 0.f; }
  }
  if (lane == 63) {
#pragma unroll
    for (int q = 0; q < 3; ++q) { wag[wid][q] = tS[q]; wag[wid][3 + q] = tT[q]; }
  }
  __syncthreads();

  // cross-wave exclusive combine + full-block totals
  float oS[3] = {0, 0, 0}, oT[3] = {0, 0, 0}, TA[3], TW[3];
  for (int w = 0; w < wid; ++w) {
#pragma unroll
    for (int q = 0; q < 3; ++q) oT[q] = oT[q] + 512.0f * oS[q] + wag[w][3 + q];
#pragma unroll
    for (int q = 0; q < 3; ++q) oS[q] += wag[w][q];
  }
#pragma unroll
  for (int q = 0; q < 3; ++q) {
    TA[q] = wag[0][q] + wag[1][q] + wag[2][q] + wag[3][q];
    TW[q] = (wag[0][3 + q] + 1536.f * wag[0][q]) + (wag[1][3 + q] + 1024.f * wag[1][q])
          + (wag[2][3 + q] + 512.f * wag[2][q]) + wag[3][3 + q];
  }

  // ---- 3. publish aggregate, wave-0 decoupled lookback, publish inclusive prefix
  float Eg[3] = {0, 0, 0}, Hg[3] = {0, 0, 0};
  if (wid == 0) {
    if (t == 0 && b > 0) {
#pragma unroll
      for (int q = 0; q < 3; ++q) { pay[12 * b + q] = TA[q]; pay[12 * b + 3 + q] = TW[q]; }
      __hip_atomic_store(&flag[b], 1u, __ATOMIC_RELEASE, __HIP_MEMORY_SCOPE_AGENT);
    }
    if (b > 0) {
      int m = 0; bool done = false;
      while (!done) {
        const int c = b - 1 - m - lane;
        int fl; float P0, P1, P2, P3, P4, P5;
        if (c >= 0) {
          unsigned int fv;
          do {
            fv = __hip_atomic_load(&flag[c], __ATOMIC_ACQUIRE, __HIP_MEMORY_SCOPE_AGENT);
            if (fv == 0u) __builtin_amdgcn_s_sleep(1);
          } while (fv == 0u);
          fl = (int)fv;
          const float* pp = pay + 12 * c + (fl == 2 ? 6 : 0);
          P0 = pp[0]; P1 = pp[1]; P2 = pp[2]; P3 = pp[3]; P4 = pp[4]; P5 = pp[5];
        } else {
          fl = 2; P0 = P1 = P2 = P3 = P4 = P5 = 0.f;   // virtual zero-prefix past block 0
        }
        const unsigned long long m2 = __ballot(fl == 2);
        const int j2 = (m2 != 0ull) ? (__ffsll(m2) - 1) : 64;
        const int lim = (j2 < 64) ? j2 : 63;
        for (int j = 0; j <= lim; ++j) {
          const float q0 = __shfl(P0, j), q1 = __shfl(P1, j), q2 = __shfl(P2, j);
          const float q3 = __shfl(P3, j), q4 = __shfl(P4, j), q5 = __shfl(P5, j);
          const float mc = (float)(m + j) * (float)CHUNK;
          Hg[0] += q3 + mc * q0; Hg[1] += q4 + mc * q1; Hg[2] += q5 + mc * q2;
          Eg[0] += q0; Eg[1] += q1; Eg[2] += q2;
        }
        if (j2 < 64) done = true; else m += 64;
      }
    }
    if (t == 0) {
      // inclusive prefix of this block: E = Eg+TA ; H = Hg + CHUNK*Eg + TW
#pragma unroll
      for (int q = 0; q < 3; ++q) {
        pay[12 * b + 6 + q] = Eg[q] + TA[q];
        pay[12 * b + 9 + q] = Hg[q] + (float)CHUNK * Eg[q] + TW[q];
      }
      __hip_atomic_store(&flag[b], 2u, __ATOMIC_RELEASE, __HIP_MEMORY_SCOPE_AGENT);
#pragma unroll
      for (int q = 0; q < 3; ++q) { shEH[q] = Eg[q]; shEH[3 + q] = Hg[q]; }
    }
  }
  __syncthreads();
#pragma unroll
  for (int q = 0; q < 3; ++q) { Eg[q] = shEH[q]; Hg[q] = shEH[3 + q]; }

  // absolute thread-entry (E0, H0)
  float E0[3], H0[3];
#pragma unroll
  for (int q = 0; q < 3; ++q) {
    E0[q] = Eg[q] + oS[q] + eS[q];
    H0[q] = Hg[q] + (float)(R * t) * Eg[q] + (oT[q] + (float)(R * lane) * oS[q] + eT[q]);
  }

  // ---- 4. fused epilogue: p -> LDS, v -> registers
  const float f0[3] = {f[0], f[1], f[2]};
  const float p0x = p0v[0], p0y = p0v[1], p0z = p0v[2];
  const float v0x = v0v[0], v0y = v0v[1], v0z = v0v[2];
  const float a1 = DTc * Cc, a2 = 0.5f * DTc * Cc, c3 = 0.5f * DTc * GZ;

  float lsum[3] = {0, 0, 0};
  float runH[3] = {H0[0], H0[1], H0[2]};
  float ve[3 * R];
#pragma unroll
  for (int g = 0; g < 2; ++g) {
    float pe[12];
#pragma unroll
    for (int e4 = 0; e4 < 4; ++e4) {
      const int e = 4 * g + e4;
      const float n1 = (float)(int)(start + t * R + e + 1);   // < 2^24, exact
      float S_[3], T_[3];
#pragma unroll
      for (int q = 0; q < 3; ++q) {
        const float curE = E0[q] + lsum[q];    // E_i
        runH[q] += curE;                       // H_i
        S_[q] = f0[q] + curE;
        T_[q] = n1 * f0[q] + runH[q];
        lsum[q] += z[3 * e + q];
      }
      ve[3 * e + 0] = v0x + Cc * S_[0];
      ve[3 * e + 1] = v0y + Cc * S_[1];
      ve[3 * e + 2] = v0z + Cc * S_[2] + GZ * n1;
      pe[3 * e4 + 0] = p0x + DTc * n1 * v0x + a1 * T_[0] - a2 * S_[0];
      pe[3 * e4 + 1] = p0y + DTc * n1 * v0y + a1 * T_[1] - a2 * S_[1];
      pe[3 * e4 + 2] = p0z + DTc * n1 * v0z + a1 * T_[2] - a2 * S_[2] + c3 * n1 * n1;
    }
#pragma unroll
    for (int u = 0; u < 3; ++u) {
      f32x4 pv = {pe[4 * u], pe[4 * u + 1], pe[4 * u + 2], pe[4 * u + 3]};
      buf[7 * t + 3 * g + u] = pv;
    }
  }
  __syncthreads();

  // ---- 5. coalesced nontemporal store of p
  {
    f32x4* dst = (f32x4*)out + (size_t)NF4 * b;
#pragma unroll
    for (int it = 0; it < 6; ++it) {
      const int q = t + BLOCK * it;
      f32x4 d = buf[physf4(q)];
      __builtin_nontemporal_store(d, dst + q);
    }
  }
  __syncthreads();

  // ---- 6. v through the same buffer
#pragma unroll
  for (int u = 0; u < 6; ++u) {
    f32x4 vv = {ve[4 * u], ve[4 * u + 1], ve[4 * u + 2], ve[4 * u + 3]};
    buf[7 * t + u] = vv;
  }
  __syncthreads();
  {
    f32x4* dst = (f32x4*)(out + (size_t)3 * KE) + (size_t)NF4 * b;
#pragma unroll
    for (int it = 0; it < 6; ++it) {
      const int q = t + BLOCK * it;
      f32x4 d = buf[physf4(q)];
      __builtin_nontemporal_store(d, dst + q);
    }
  }
}

extern "C" void kernel_launch(void* const* d_in, const int* in_sizes, int n_in,
                              void* d_out, int out_size, void* d_ws, size_t ws_size,
                              hipStream_t stream) {
  const float* f  = (const float*)d_in[0];
  const float* p0 = (const float*)d_in[1];
  const float* v0 = (const float*)d_in[2];
  float* out = (float*)d_out;
  unsigned int* flag = (unsigned int*)d_ws;          // NB uints
  float* pay = (float*)d_ws + NB;                    // NB * 12 floats
  hipMemsetAsync(flag, 0, NB * sizeof(unsigned int), stream);
  k_fused<<<NB, BLOCK, 0, stream>>>(f, flag, pay, p0, v0, out);
}

// Round 6
// 83.741 us; speedup vs baseline: 4.7010x; 4.7010x over previous
//
#include <hip/hip_runtime.h>

// p/v trajectory double-scan, K = 2^23 fp32 3-vectors. Reduce-then-scan, 3 kernels.
// Aligned-stream formulation: z_m = f[m]; E_i = excl prefix(z); H_i = sum_{m<=i} E_m.
// S_i = f0 + E_i, T_i = (i+1) f0 + H_i;
//   v_i = v0 + Cc*S_i + GZ*(i+1) e3
//   p_i = p0 + DT*(i+1)*v0 + DT*Cc*T_i - DT/2*Cc*S_i + DT/2*GZ*(i+1)^2 e3
// Segment operator on (A = sum z, W = sum of seg-local excl prefixes):
//   concat X(left) Y(right): W = W_X + L_Y*A_X + W_Y ; A = A_X + A_Y.
// Lessons: r3 — strided nt STORES amplify HBM writes 2.6x (reads are fine);
//          r5 — agent-scope lookback spin serializes across XCDs (461us). Keep 3 kernels.

namespace {
constexpr int  KE    = 8388608;               // 2^23
constexpr int  CHUNK = 1024;                  // elements per scan block
constexpr int  NB    = KE / CHUNK;            // 8192
constexpr int  BLOCK = 256;
constexpr int  R     = CHUNK / BLOCK;         // 4 elements/thread (contiguous)
constexpr int  NF4   = 3 * CHUNK / 4;         // 768 float4s per block (per output)
constexpr int  PRET  = 1024;                  // k_pre threads
constexpr int  BPT   = NB / PRET;             // 8 chunks per k_pre thread
constexpr float DTc = 0.01f;
constexpr float Cc  = 0.01f / 1.5f;           // DT/M
constexpr float GZ  = -0.01f * 9.81f;         // DT * (-G)
typedef float f32x4 __attribute__((ext_vector_type(4)));
}

// ---------- k_agg: per-chunk A = sum z, Bw = sum j*z  (j = in-chunk position) ----------
__global__ __launch_bounds__(BLOCK) void k_agg(const float* __restrict__ f,
                                               float* __restrict__ W) {
  const int b = blockIdx.x, t = threadIdx.x;
  const int lane = t & 63, wid = t >> 6;
  const f32x4* src = (const f32x4*)(f + (size_t)3 * CHUNK * b);
  float A[3], Bw[3];
  {
    f32x4 d0 = src[3 * t], d1 = src[3 * t + 1], d2 = src[3 * t + 2];
    const float j0 = (float)(4 * t), j1 = j0 + 1.f, j2 = j0 + 2.f, j3 = j0 + 3.f;
    A[0] = d0.x + d0.w + d1.z + d2.y;  Bw[0] = j0 * d0.x + j1 * d0.w + j2 * d1.z + j3 * d2.y;
    A[1] = d0.y + d1.x + d1.w + d2.z;  Bw[1] = j0 * d0.y + j1 * d1.x + j2 * d1.w + j3 * d2.z;
    A[2] = d0.z + d1.y + d2.x + d2.w;  Bw[2] = j0 * d0.z + j1 * d1.y + j2 * d2.x + j3 * d2.w;
  }
#pragma unroll
  for (int d = 32; d >= 1; d >>= 1) {
#pragma unroll
    for (int q = 0; q < 3; ++q) {
      A[q]  += __shfl_down(A[q], d);
      Bw[q] += __shfl_down(Bw[q], d);
    }
  }
  __shared__ float wag[4][6];
  if (lane == 0) {
#pragma unroll
    for (int q = 0; q < 3; ++q) { wag[wid][q] = A[q]; wag[wid][3 + q] = Bw[q]; }
  }
  __syncthreads();
  if (t == 0) {
#pragma unroll
    for (int q = 0; q < 3; ++q) {
      W[q * NB + b]       = wag[0][q] + wag[1][q] + wag[2][q] + wag[3][q];
      W[(3 + q) * NB + b] = wag[0][3 + q] + wag[1][3 + q] + wag[2][3 + q] + wag[3][3 + q];
    }
  }
}

// ---------- k_pre: cross-chunk exclusive (Eg, Hg) per chunk, fp64, 1024 threads ----------
__global__ __launch_bounds__(PRET) void k_pre(const float* __restrict__ W,
                                              float* __restrict__ W2) {
  const int t = threadIdx.x, lane = t & 63, wid = t >> 6;   // 16 waves
  // streaming thread totals over BPT chunks (recompute per-chunk later; W is L2-hot)
  double tA[3] = {0, 0, 0}, tW[3] = {0, 0, 0};
#pragma unroll
  for (int k = 0; k < BPT; ++k) {
    const int c = BPT * t + k;
#pragma unroll
    for (int q = 0; q < 3; ++q) {
      const double a  = (double)W[q * NB + c];
      const double bw = (double)W[(3 + q) * NB + c];
      const double wc = (double)(CHUNK - 1) * a - bw;   // W over chunk
      tW[q] += (double)((BPT - 1 - k) * CHUNK) * a + wc;
      tA[q] += a;
    }
  }
#pragma unroll
  for (int d = 1; d < 64; d <<= 1) {
    double pA[3], pW[3];
#pragma unroll
    for (int q = 0; q < 3; ++q) { pA[q] = __shfl_up(tA[q], d); pW[q] = __shfl_up(tW[q], d); }
    if (lane >= d) {
      const double Ld = (double)(d * BPT * CHUNK);
#pragma unroll
      for (int q = 0; q < 3; ++q) { tW[q] = pW[q] + Ld * pA[q] + tW[q]; tA[q] += pA[q]; }
    }
  }
  double eA[3], eW[3];
#pragma unroll
  for (int q = 0; q < 3; ++q) { eA[q] = __shfl_up(tA[q], 1); eW[q] = __shfl_up(tW[q], 1); }
  if (lane == 0) {
#pragma unroll
    for (int q = 0; q < 3; ++q) { eA[q] = 0.0; eW[q] = 0.0; }
  }
  __shared__ double wagd[16][6];
  if (lane == 63) {
#pragma unroll
    for (int q = 0; q < 3; ++q) { wagd[wid][q] = tA[q]; wagd[wid][3 + q] = tW[q]; }
  }
  __syncthreads();
  double oA[3] = {0, 0, 0}, oW[3] = {0, 0, 0};
  for (int w = 0; w < wid; ++w) {
#pragma unroll
    for (int q = 0; q < 3; ++q) oW[q] = oW[q] + (double)(64 * BPT * CHUNK) * oA[q] + wagd[w][3 + q];
#pragma unroll
    for (int q = 0; q < 3; ++q) oA[q] += wagd[w][q];
  }
  double Ex[3], Hx[3];
#pragma unroll
  for (int q = 0; q < 3; ++q) {
    Ex[q] = oA[q] + eA[q];
    Hx[q] = oW[q] + (double)(lane * BPT * CHUNK) * oA[q] + eW[q];
  }
#pragma unroll
  for (int k = 0; k < BPT; ++k) {
    const int c = BPT * t + k;
#pragma unroll
    for (int q = 0; q < 3; ++q) {
      W2[6 * c + q]     = (float)Ex[q];          // Eg: excl elem-sum before chunk c
      W2[6 * c + 3 + q] = (float)Hx[q];          // Hg: sum of E over elems before chunk c
      const double a  = (double)W[q * NB + c];
      const double bw = (double)W[(3 + q) * NB + c];
      const double wc = (double)(CHUNK - 1) * a - bw;
      Hx[q] += (double)CHUNK * Ex[q] + wc;
      Ex[q] += a;
    }
  }
}

// ---------- k_scan: register load + scan + fused epilogue, single LDS store round-trip ----------
__global__ __launch_bounds__(BLOCK, 5) void k_scan(const float* __restrict__ f,
                                                   const float* __restrict__ W2,
                                                   const float* __restrict__ p0v,
                                                   const float* __restrict__ v0v,
                                                   float* __restrict__ out) {
  const int b = blockIdx.x, t = threadIdx.x;
  const int lane = t & 63, wid = t >> 6;
  const long start = (long)b * CHUNK;

  __shared__ f32x4 buf[7 * BLOCK];    // 28672 B: per thread 3 p-f4 + 3 v-f4 + 1 pad
  __shared__ float wag[4][6];

  // ---- 1. direct register load: thread's 4 elements = 3 contiguous float4s
  float z[3 * R];
  {
    const f32x4* src = (const f32x4*)(f + 3 * start) + 3 * t;
#pragma unroll
    for (int u = 0; u < 3; ++u) {
      f32x4 d = src[u];
      z[4 * u] = d.x; z[4 * u + 1] = d.y; z[4 * u + 2] = d.z; z[4 * u + 3] = d.w;
    }
  }

  // per-thread aggregates: A = sum z, W = sum (R-1-e)*z
  float tS[3] = {0, 0, 0}, tT[3] = {0, 0, 0};
#pragma unroll
  for (int e = 0; e < R; ++e) {
    const float wt = (float)(R - 1 - e);
#pragma unroll
    for (int q = 0; q < 3; ++q) { float v = z[3 * e + q]; tS[q] += v; tT[q] += wt * v; }
  }
  // wave Kogge-Stone with (A,W) operator; right-segment length at step d is R*d
#pragma unroll
  for (int d = 1; d < 64; d <<= 1) {
    float pS[3], pT[3];
#pragma unroll
    for (int q = 0; q < 3; ++q) { pS[q] = __shfl_up(tS[q], d); pT[q] = __shfl_up(tT[q], d); }
    if (lane >= d) {
      const float Ld = (float)(R * d);
#pragma unroll
      for (int q = 0; q < 3; ++q) { tT[q] = pT[q] + Ld * pS[q] + tT[q]; tS[q] += pS[q]; }
    }
  }
  float eS[3], eT[3];
#pragma unroll
  for (int q = 0; q < 3; ++q) { eS[q] = __shfl_up(tS[q], 1); eT[q] = __shfl_up(tT[q], 1); }
  if (lane == 0) {
#pragma unroll
    for (int q = 0; q < 3; ++q) { eS[q] = 0.f; eT[q] = 0.f; }
  }
  if (lane == 63) {
#pragma unroll
    for (int q = 0; q < 3; ++q) { wag[wid][q] = tS[q]; wag[wid][3 + q] = tT[q]; }
  }
  __syncthreads();                       // barrier 1
  float oS[3] = {0, 0, 0}, oT[3] = {0, 0, 0};
  for (int w = 0; w < wid; ++w) {        // wave segment length = 64*R = 256
#pragma unroll
    for (int q = 0; q < 3; ++q) oT[q] = oT[q] + 256.0f * oS[q] + wag[w][3 + q];
#pragma unroll
    for (int q = 0; q < 3; ++q) oS[q] += wag[w][q];
  }
  // absolute thread-entry (E0, H0)
  float E0[3], H0[3];
#pragma unroll
  for (int q = 0; q < 3; ++q) {
    const float Eg = W2[6 * b + q], Hg = W2[6 * b + 3 + q];
    E0[q] = Eg + oS[q] + eS[q];
    H0[q] = Hg + (float)(R * t) * Eg + (oT[q] + (float)(R * lane) * oS[q] + eT[q]);
  }

  // ---- 2. fused epilogue: p -> buf[7t+0..2], v -> buf[7t+3..5]
  const float f0[3] = {f[0], f[1], f[2]};
  const float p0x = p0v[0], p0y = p0v[1], p0z = p0v[2];
  const float v0x = v0v[0], v0y = v0v[1], v0z = v0v[2];
  const float a1 = DTc * Cc, a2 = 0.5f * DTc * Cc, c3 = 0.5f * DTc * GZ;

  float lsum[3] = {0, 0, 0};
  float runH[3] = {H0[0], H0[1], H0[2]};
  float pe[12], ve[12];
#pragma unroll
  for (int e = 0; e < R; ++e) {
    const float n1 = (float)(int)(start + t * R + e + 1);   // <= 2^23, exact in fp32
    float S_[3], T_[3];
#pragma unroll
    for (int q = 0; q < 3; ++q) {
      const float curE = E0[q] + lsum[q];    // E_i
      runH[q] += curE;                       // H_i
      S_[q] = f0[q] + curE;
      T_[q] = n1 * f0[q] + runH[q];
      lsum[q] += z[3 * e + q];
    }
    ve[3 * e + 0] = v0x + Cc * S_[0];
    ve[3 * e + 1] = v0y + Cc * S_[1];
    ve[3 * e + 2] = v0z + Cc * S_[2] + GZ * n1;
    pe[3 * e + 0] = p0x + DTc * n1 * v0x + a1 * T_[0] - a2 * S_[0];
    pe[3 * e + 1] = p0y + DTc * n1 * v0y + a1 * T_[1] - a2 * S_[1];
    pe[3 * e + 2] = p0z + DTc * n1 * v0z + a1 * T_[2] - a2 * S_[2] + c3 * n1 * n1;
  }
#pragma unroll
  for (int u = 0; u < 3; ++u) {
    f32x4 pv = {pe[4 * u], pe[4 * u + 1], pe[4 * u + 2], pe[4 * u + 3]};
    f32x4 vv = {ve[4 * u], ve[4 * u + 1], ve[4 * u + 2], ve[4 * u + 3]};
    buf[7 * t + u]     = pv;
    buf[7 * t + 3 + u] = vv;
  }
  __syncthreads();                       // barrier 2

  // ---- 3. coalesced nontemporal stores of p then v (both read-only on buf)
  {
    f32x4* dst = (f32x4*)out + (size_t)NF4 * b;
#pragma unroll
    for (int it = 0; it < 3; ++it) {
      const int q = t + BLOCK * it;                  // 0..767
      f32x4 d = buf[7 * (q / 3) + q % 3];
      __builtin_nontemporal_store(d, dst + q);
    }
  }
  {
    f32x4* dst = (f32x4*)(out + (size_t)3 * KE) + (size_t)NF4 * b;
#pragma unroll
    for (int it = 0; it < 3; ++it) {
      const int q = t + BLOCK * it;
      f32x4 d = buf[7 * (q / 3) + 3 + q % 3];
      __builtin_nontemporal_store(d, dst + q);
    }
  }
}

extern "C" void kernel_launch(void* const* d_in, const int* in_sizes, int n_in,
                              void* d_out, int out_size, void* d_ws, size_t ws_size,
                              hipStream_t stream) {
  const float* f  = (const float*)d_in[0];
  const float* p0 = (const float*)d_in[1];
  const float* v0 = (const float*)d_in[2];
  float* out = (float*)d_out;
  float* W   = (float*)d_ws;            // 6*NB floats: A[3][NB], Bw[3][NB]   (192 KB)
  float* W2  = W + 6 * NB;              // 6*NB floats: per-chunk (Eg[3], Hg[3]) (192 KB)
  k_agg <<<NB, BLOCK, 0, stream>>>(f, W);
  k_pre <<<1, PRET, 0, stream>>>(W, W2);
  k_scan<<<NB, BLOCK, 0, stream>>>(f, W2, p0, v0, out);
}

// Round 7
// 77.999 us; speedup vs baseline: 5.0470x; 1.0736x over previous
//
#include <hip/hip_runtime.h>

// p/v trajectory double-scan, K = 2^23 fp32 3-vectors. Reduce-then-scan, 3 kernels.
// Aligned-stream formulation: z_m = f[m]; E_i = excl prefix(z); H_i = sum_{m<=i} E_m.
// S_i = f0 + E_i, T_i = (i+1) f0 + H_i;
//   v_i = v0 + Cc*S_i + GZ*(i+1) e3
//   p_i = p0 + DT*(i+1)*v0 + DT*Cc*T_i - DT/2*Cc*S_i + DT/2*GZ*(i+1)^2 e3
// Segment operator on (A = sum z, W = sum of seg-local excl prefixes):
//   concat X(left) Y(right): W = W_X + L_Y*A_X + W_Y ; A = A_X + A_Y.
// Lessons: r3 — strided nt STORES amplify HBM writes 2.6x; r5 — agent-scope
// lookback spin serializes across XCDs; r6 — tiny per-block work in k_agg and
// strided register input loads both cost; plane-swizzled LDS fixes all IO.

namespace {
constexpr int  KE    = 8388608;               // 2^23
constexpr int  CHUNK = 2048;                  // elements per scan block
constexpr int  NB    = KE / CHUNK;            // 4096
constexpr int  ABLK  = 256;                   // k_agg block
constexpr int  SBLK  = 512;                   // k_scan block (8 waves)
constexpr int  R     = CHUNK / SBLK;          // 4 elements/thread
constexpr int  NF4   = 3 * CHUNK / 4;         // 1536 f4 per chunk per output
constexpr int  PLANE = NF4 / 3 + 1;           // 513 f4 per plane (odd stride)
constexpr int  PRET  = 1024;                  // k_pre threads
constexpr int  BPT   = NB / PRET;             // 4 chunks per k_pre thread
constexpr float DTc = 0.01f;
constexpr float Cc  = 0.01f / 1.5f;           // DT/M
constexpr float GZ  = -0.01f * 9.81f;         // DT * (-G)
typedef float f32x4 __attribute__((ext_vector_type(4)));
}

// ---------- k_agg: per-chunk A = sum z, Bw = sum j*z  (r4-proven geometry) ----------
__global__ __launch_bounds__(ABLK) void k_agg(const float* __restrict__ f,
                                              float* __restrict__ W) {
  const int b = blockIdx.x, t = threadIdx.x;
  const int lane = t & 63, wid = t >> 6;
  const f32x4* src = (const f32x4*)(f + (size_t)3 * CHUNK * b);
  float A[3] = {0.f, 0.f, 0.f}, Bw[3] = {0.f, 0.f, 0.f};
#pragma unroll
  for (int it = 0; it < 2; ++it) {
    int q3 = it * ABLK + t;                   // triple index, elems 4q3..4q3+3
    f32x4 d0 = src[3 * q3], d1 = src[3 * q3 + 1], d2 = src[3 * q3 + 2];
    float j0 = (float)(4 * q3), j1 = j0 + 1.f, j2 = j0 + 2.f, j3 = j0 + 3.f;
    A[0] += d0.x; Bw[0] += j0 * d0.x;  A[1] += d0.y; Bw[1] += j0 * d0.y;  A[2] += d0.z; Bw[2] += j0 * d0.z;
    A[0] += d0.w; Bw[0] += j1 * d0.w;  A[1] += d1.x; Bw[1] += j1 * d1.x;  A[2] += d1.y; Bw[2] += j1 * d1.y;
    A[0] += d1.z; Bw[0] += j2 * d1.z;  A[1] += d1.w; Bw[1] += j2 * d1.w;  A[2] += d2.x; Bw[2] += j2 * d2.x;
    A[0] += d2.y; Bw[0] += j3 * d2.y;  A[1] += d2.z; Bw[1] += j3 * d2.z;  A[2] += d2.w; Bw[2] += j3 * d2.w;
  }
#pragma unroll
  for (int d = 32; d >= 1; d >>= 1) {
#pragma unroll
    for (int q = 0; q < 3; ++q) {
      A[q]  += __shfl_down(A[q], d);
      Bw[q] += __shfl_down(Bw[q], d);
    }
  }
  __shared__ float wag[4][6];
  if (lane == 0) {
#pragma unroll
    for (int q = 0; q < 3; ++q) { wag[wid][q] = A[q]; wag[wid][3 + q] = Bw[q]; }
  }
  __syncthreads();
  if (t == 0) {
#pragma unroll
    for (int q = 0; q < 3; ++q) {
      W[q * NB + b]       = wag[0][q] + wag[1][q] + wag[2][q] + wag[3][q];
      W[(3 + q) * NB + b] = wag[0][3 + q] + wag[1][3 + q] + wag[2][3 + q] + wag[3][3 + q];
    }
  }
}

// ---------- k_pre: cross-chunk exclusive (Eg, Hg) per chunk, fp64 (r4-proven) ----------
__global__ __launch_bounds__(PRET) void k_pre(const float* __restrict__ W,
                                              float* __restrict__ W2) {
  const int t = threadIdx.x, lane = t & 63, wid = t >> 6;   // 16 waves
  double Ac[BPT][3], Wc[BPT][3];
#pragma unroll
  for (int k = 0; k < BPT; ++k) {
    const int c = BPT * t + k;
#pragma unroll
    for (int q = 0; q < 3; ++q) {
      double a  = (double)W[q * NB + c];
      double bw = (double)W[(3 + q) * NB + c];
      Ac[k][q] = a;
      Wc[k][q] = (double)(CHUNK - 1) * a - bw;   // sum (CHUNK-1-j)*z over chunk
    }
  }
  double tA[3] = {0, 0, 0}, tW[3] = {0, 0, 0};
#pragma unroll
  for (int k = 0; k < BPT; ++k) {
#pragma unroll
    for (int q = 0; q < 3; ++q) {
      tW[q] += (double)((BPT - 1 - k) * CHUNK) * Ac[k][q] + Wc[k][q];
      tA[q] += Ac[k][q];
    }
  }
#pragma unroll
  for (int d = 1; d < 64; d <<= 1) {
    double pA[3], pW[3];
#pragma unroll
    for (int q = 0; q < 3; ++q) { pA[q] = __shfl_up(tA[q], d); pW[q] = __shfl_up(tW[q], d); }
    if (lane >= d) {
      const double Ld = (double)(d * BPT * CHUNK);
#pragma unroll
      for (int q = 0; q < 3; ++q) { tW[q] = pW[q] + Ld * pA[q] + tW[q]; tA[q] += pA[q]; }
    }
  }
  double eA[3], eW[3];
#pragma unroll
  for (int q = 0; q < 3; ++q) { eA[q] = __shfl_up(tA[q], 1); eW[q] = __shfl_up(tW[q], 1); }
  if (lane == 0) {
#pragma unroll
    for (int q = 0; q < 3; ++q) { eA[q] = 0.0; eW[q] = 0.0; }
  }
  __shared__ double wagd[16][6];
  if (lane == 63) {
#pragma unroll
    for (int q = 0; q < 3; ++q) { wagd[wid][q] = tA[q]; wagd[wid][3 + q] = tW[q]; }
  }
  __syncthreads();
  double oA[3] = {0, 0, 0}, oW[3] = {0, 0, 0};
  for (int w = 0; w < wid; ++w) {
#pragma unroll
    for (int q = 0; q < 3; ++q) oW[q] = oW[q] + (double)(64 * BPT * CHUNK) * oA[q] + wagd[w][3 + q];
#pragma unroll
    for (int q = 0; q < 3; ++q) oA[q] += wagd[w][q];
  }
  double Ex[3], Hx[3];
#pragma unroll
  for (int q = 0; q < 3; ++q) {
    Ex[q] = oA[q] + eA[q];
    Hx[q] = oW[q] + (double)(lane * BPT * CHUNK) * oA[q] + eW[q];
  }
#pragma unroll
  for (int k = 0; k < BPT; ++k) {
    const int c = BPT * t + k;
#pragma unroll
    for (int q = 0; q < 3; ++q) {
      W2[6 * c + q]     = (float)Ex[q];          // Eg: excl elem-sum before chunk c
      W2[6 * c + 3 + q] = (float)Hx[q];          // Hg: sum of E over elems before chunk c
      Hx[q] += (double)CHUNK * Ex[q] + Wc[k][q];
      Ex[q] += Ac[k][q];
    }
  }
}

// ---------- k_scan: plane-swizzled LDS, 3 barriers, 1 output round-trip ----------
// f4 #i of a stream lives at buf[plane = i%3][slot = i/3]; plane stride 513
// (odd, ==1 mod 8) -> stage-in/readout ~2-way, thread-slot access conflict-free.
__global__ __launch_bounds__(SBLK, 3) void k_scan(const float* __restrict__ f,
                                                  const float* __restrict__ W2,
                                                  const float* __restrict__ p0v,
                                                  const float* __restrict__ v0v,
                                                  float* __restrict__ out) {
  const int b = blockIdx.x, t = threadIdx.x;
  const int lane = t & 63, wid = t >> 6;
  const long start = (long)b * CHUNK;

  __shared__ f32x4 buf[6 * PLANE];    // 49248 B: planes 0-2 = input/p, 3-5 = v
  __shared__ float wag[8][6];

  // ---- 1. stage-in: coalesced global read -> plane layout
  {
    const f32x4* src = (const f32x4*)(f + 3 * start);
#pragma unroll
    for (int it = 0; it < 3; ++it) {
      const int q = t + SBLK * it;               // 0..1535
      buf[PLANE * (q % 3) + q / 3] = src[q];
    }
  }
  __syncthreads();                               // barrier 1

  // ---- 2. z: thread t's f4s {3t,3t+1,3t+2} = planes 0..2 at slot t (conflict-free)
  float z[3 * R];
#pragma unroll
  for (int u = 0; u < 3; ++u) {
    f32x4 d = buf[PLANE * u + t];
    z[4 * u] = d.x; z[4 * u + 1] = d.y; z[4 * u + 2] = d.z; z[4 * u + 3] = d.w;
  }

  // per-thread aggregates: A = sum z, W = sum (R-1-e)*z
  float tS[3] = {0, 0, 0}, tT[3] = {0, 0, 0};
#pragma unroll
  for (int e = 0; e < R; ++e) {
    const float wt = (float)(R - 1 - e);
#pragma unroll
    for (int q = 0; q < 3; ++q) { float v = z[3 * e + q]; tS[q] += v; tT[q] += wt * v; }
  }
  // wave Kogge-Stone with (A,W) operator; right-segment length at step d is R*d
#pragma unroll
  for (int d = 1; d < 64; d <<= 1) {
    float pS[3], pT[3];
#pragma unroll
    for (int q = 0; q < 3; ++q) { pS[q] = __shfl_up(tS[q], d); pT[q] = __shfl_up(tT[q], d); }
    if (lane >= d) {
      const float Ld = (float)(R * d);
#pragma unroll
      for (int q = 0; q < 3; ++q) { tT[q] = pT[q] + Ld * pS[q] + tT[q]; tS[q] += pS[q]; }
    }
  }
  float eS[3], eT[3];
#pragma unroll
  for (int q = 0; q < 3; ++q) { eS[q] = __shfl_up(tS[q], 1); eT[q] = __shfl_up(tT[q], 1); }
  if (lane == 0) {
#pragma unroll
    for (int q = 0; q < 3; ++q) { eS[q] = 0.f; eT[q] = 0.f; }
  }
  if (lane == 63) {
#pragma unroll
    for (int q = 0; q < 3; ++q) { wag[wid][q] = tS[q]; wag[wid][3 + q] = tT[q]; }
  }
  __syncthreads();                               // barrier 2
  float oS[3] = {0, 0, 0}, oT[3] = {0, 0, 0};
  for (int w = 0; w < wid; ++w) {                // wave segment = 64*R = 256 elems
#pragma unroll
    for (int q = 0; q < 3; ++q) oT[q] = oT[q] + 256.0f * oS[q] + wag[w][3 + q];
#pragma unroll
    for (int q = 0; q < 3; ++q) oS[q] += wag[w][q];
  }
  // absolute thread-entry (E0, H0)
  float E0[3], H0[3];
#pragma unroll
  for (int q = 0; q < 3; ++q) {
    const float Eg = W2[6 * b + q], Hg = W2[6 * b + 3 + q];
    E0[q] = Eg + oS[q] + eS[q];
    H0[q] = Hg + (float)(R * t) * Eg + (oT[q] + (float)(R * lane) * oS[q] + eT[q]);
  }

  // ---- 3. fused epilogue -> plane writes (WAR on planes 0..2 is thread-local)
  const float f0[3] = {f[0], f[1], f[2]};
  const float p0x = p0v[0], p0y = p0v[1], p0z = p0v[2];
  const float v0x = v0v[0], v0y = v0v[1], v0z = v0v[2];
  const float a1 = DTc * Cc, a2 = 0.5f * DTc * Cc, c3 = 0.5f * DTc * GZ;

  float lsum[3] = {0, 0, 0};
  float runH[3] = {H0[0], H0[1], H0[2]};
  float pe[12], ve[12];
#pragma unroll
  for (int e = 0; e < R; ++e) {
    const float n1 = (float)(int)(start + t * R + e + 1);   // <= 2^23, exact in fp32
    float S_[3], T_[3];
#pragma unroll
    for (int q = 0; q < 3; ++q) {
      const float curE = E0[q] + lsum[q];    // E_i
      runH[q] += curE;                       // H_i
      S_[q] = f0[q] + curE;
      T_[q] = n1 * f0[q] + runH[q];
      lsum[q] += z[3 * e + q];
    }
    ve[3 * e + 0] = v0x + Cc * S_[0];
    ve[3 * e + 1] = v0y + Cc * S_[1];
    ve[3 * e + 2] = v0z + Cc * S_[2] + GZ * n1;
    pe[3 * e + 0] = p0x + DTc * n1 * v0x + a1 * T_[0] - a2 * S_[0];
    pe[3 * e + 1] = p0y + DTc * n1 * v0y + a1 * T_[1] - a2 * S_[1];
    pe[3 * e + 2] = p0z + DTc * n1 * v0z + a1 * T_[2] - a2 * S_[2] + c3 * n1 * n1;
  }
#pragma unroll
  for (int u = 0; u < 3; ++u) {
    f32x4 pv = {pe[4 * u], pe[4 * u + 1], pe[4 * u + 2], pe[4 * u + 3]};
    f32x4 vv = {ve[4 * u], ve[4 * u + 1], ve[4 * u + 2], ve[4 * u + 3]};
    buf[PLANE * u + t]       = pv;     // p f4 #(3t+u)
    buf[PLANE * (3 + u) + t] = vv;     // v f4 #(3t+u)
  }
  __syncthreads();                               // barrier 3

  // ---- 4. coalesced nontemporal stores of p then v
  {
    f32x4* dst = (f32x4*)out + (size_t)NF4 * b;
#pragma unroll
    for (int it = 0; it < 3; ++it) {
      const int q = t + SBLK * it;
      f32x4 d = buf[PLANE * (q % 3) + q / 3];
      __builtin_nontemporal_store(d, dst + q);
    }
  }
  {
    f32x4* dst = (f32x4*)(out + (size_t)3 * KE) + (size_t)NF4 * b;
#pragma unroll
    for (int it = 0; it < 3; ++it) {
      const int q = t + SBLK * it;
      f32x4 d = buf[PLANE * (3 + q % 3) + q / 3];
      __builtin_nontemporal_store(d, dst + q);
    }
  }
}

extern "C" void kernel_launch(void* const* d_in, const int* in_sizes, int n_in,
                              void* d_out, int out_size, void* d_ws, size_t ws_size,
                              hipStream_t stream) {
  const float* f  = (const float*)d_in[0];
  const float* p0 = (const float*)d_in[1];
  const float* v0 = (const float*)d_in[2];
  float* out = (float*)d_out;
  float* W   = (float*)d_ws;            // 6*NB floats: A[3][NB], Bw[3][NB]
  float* W2  = W + 6 * NB;              // 6*NB floats: per-chunk (Eg[3], Hg[3])
  k_agg <<<NB, ABLK, 0, stream>>>(f, W);
  k_pre <<<1, PRET, 0, stream>>>(W, W2);
  k_scan<<<NB, SBLK, 0, stream>>>(f, W2, p0, v0, out);
}